// Round 2
// baseline (380.529 us; speedup 1.0000x reference)
//
#include <hip/hip_runtime.h>
#include <hip/hip_bf16.h>

#define N 8192
#define IN_F 128
#define OUT_F 64
#define ALPHA 0.2f

#define RB 32      // rows per block (main kernel)
#define JT 128     // j-tile
#define TB 512     // threads per block (main kernel)
#define PSTRIDE 132  // padded P row stride (floats), 16B-aligned, bank-spread

typedef int iv4 __attribute__((ext_vector_type(4)));

// monotone float->uint map so atomicMax works for (possibly negative) floats
__device__ __forceinline__ unsigned fmap(float x) {
  unsigned b = __float_as_uint(x);
  return (b & 0x80000000u) ? ~b : (b | 0x80000000u);
}
__device__ __forceinline__ float funmap(unsigned u) {
  unsigned b = (u & 0x80000000u) ? (u & 0x7FFFFFFFu) : ~u;
  return __uint_as_float(b);
}

// Kernel A: h = input @ W ; f1 = h @ a1 ; f2 = h @ a2 ; gmax = max_j f2[j]
// one wave per row, 4 rows per block
__global__ __launch_bounds__(256) void gat_prep(
    const float* __restrict__ input, const float* __restrict__ W,
    const float* __restrict__ a,
    float* __restrict__ h, float* __restrict__ f1, float* __restrict__ f2,
    unsigned* __restrict__ gmax)
{
  __shared__ float Ws[IN_F * OUT_F];   // 32 KB
  __shared__ float ins[4][IN_F];       // 2 KB
  int t = threadIdx.x;

  const float4* W4 = (const float4*)W;
  float4* Ws4 = (float4*)Ws;
#pragma unroll
  for (int k = 0; k < 8; ++k) Ws4[t + 256 * k] = W4[t + 256 * k];

  int row0 = blockIdx.x * 4;
  const float4* in4 = (const float4*)(input + (size_t)row0 * IN_F);
  float4* ins4 = (float4*)(&ins[0][0]);
  if (t < 128) ins4[t] = in4[t];
  __syncthreads();

  int w = t >> 6;        // wave id -> row within block
  int o = t & 63;        // output feature
  int i = row0 + w;

  float acc = 0.f;
#pragma unroll 16
  for (int k = 0; k < IN_F; ++k) acc += ins[w][k] * Ws[k * OUT_F + o];
  h[(size_t)i * OUT_F + o] = acc;

  float p1 = acc * a[o];
  float p2 = acc * a[OUT_F + o];
#pragma unroll
  for (int m = 32; m >= 1; m >>= 1) {
    p1 += __shfl_xor(p1, m, 64);
    p2 += __shfl_xor(p2, m, 64);
  }
  if (o == 0) {
    f1[i] = p1;
    f2[i] = p2;
    atomicMax(gmax, fmap(p2));
  }
}

// Kernel B: fused masked-softmax attention + PV + ELU.
// One block = 32 rows. Iterate j in tiles of 128; stage H-tile (LDS) and
// compute P-tile (exp of masked scores) on the fly; accumulate PV in registers.
// Softmax shift m_i = lrelu(f1[i] + max_j f2[j]) is an exact upper bound
// (leaky_relu monotone), so no online rescaling is needed.
__global__ __launch_bounds__(TB) void gat_main(
    const int* __restrict__ adj, const float* __restrict__ h,
    const float* __restrict__ f1, const float* __restrict__ f2,
    const unsigned* __restrict__ gmaxp, float* __restrict__ out)
{
  __shared__ float Hs[JT * OUT_F];       // 32 KB, [j][o]
  __shared__ float Ps[RB * PSTRIDE];     // ~16.5 KB, [r][j] padded
  __shared__ float Ls[RB];
  __shared__ float Ms[RB];
  __shared__ float F1s[RB];

  int t = threadIdx.x;
  int i0 = blockIdx.x * RB;

  if (t < RB) {
    float gmax = funmap(*gmaxp);
    float f1v = f1[i0 + t];
    F1s[t] = f1v;
    float e = f1v + gmax;
    Ms[t] = e > 0.f ? e : ALPHA * e;
  }

  // P-staging identity: 32 lanes per row, int4 over 128 j; two row passes
  int jq = t & 31;
  int rp = t >> 5;          // 0..15
  float lsum0 = 0.f, lsum1 = 0.f;

  // PV identity: row rc, output quad o4
  int o4 = t & 15;
  int rc = t >> 4;          // 0..31
  float acc0 = 0.f, acc1 = 0.f, acc2 = 0.f, acc3 = 0.f;

  for (int jt = 0; jt < N / JT; ++jt) {
    int j0 = jt * JT;
    __syncthreads();   // protect Hs/Ps from prev-iter readers; F1s/Ms ready

    // stage H tile (coalesced float4)
    const float4* Hg4 = (const float4*)(h + (size_t)j0 * OUT_F);
    float4* Hs4 = (float4*)Hs;
#pragma unroll
    for (int k = 0; k < 4; ++k) Hs4[t + TB * k] = Hg4[t + TB * k];

    // compute P tile: p = adj ? exp(lrelu(f1+f2) - m) : 0
    const float4* f2g4 = (const float4*)(f2 + j0);
#pragma unroll
    for (int p = 0; p < 2; ++p) {
      int r = p * 16 + rp;
      const iv4* arow = (const iv4*)(adj + (size_t)(i0 + r) * N + j0);
      iv4 av = __builtin_nontemporal_load(&arow[jq]);
      float4 fv = f2g4[jq];
      float f1v = F1s[r], mv = Ms[r];
      float4 pv;
      float e;
      e = f1v + fv.x; e = e > 0.f ? e : ALPHA * e; pv.x = (av.x > 0) ? __expf(e - mv) : 0.f;
      e = f1v + fv.y; e = e > 0.f ? e : ALPHA * e; pv.y = (av.y > 0) ? __expf(e - mv) : 0.f;
      e = f1v + fv.z; e = e > 0.f ? e : ALPHA * e; pv.z = (av.z > 0) ? __expf(e - mv) : 0.f;
      e = f1v + fv.w; e = e > 0.f ? e : ALPHA * e; pv.w = (av.w > 0) ? __expf(e - mv) : 0.f;
      *(float4*)&Ps[r * PSTRIDE + jq * 4] = pv;
      float s = pv.x + pv.y + pv.z + pv.w;
      if (p == 0) lsum0 += s; else lsum1 += s;
    }
    __syncthreads();

    // PV: acc[o4*4+k] += sum_j P[rc][j] * H[j][o4*4+k]
    const float* prow = &Ps[rc * PSTRIDE];
#pragma unroll 8
    for (int jj = 0; jj < JT; jj += 4) {
      float4 pv = *(const float4*)&prow[jj];
      float4 h0 = *(const float4*)&Hs[(jj + 0) * OUT_F + o4 * 4];
      float4 h1 = *(const float4*)&Hs[(jj + 1) * OUT_F + o4 * 4];
      float4 h2 = *(const float4*)&Hs[(jj + 2) * OUT_F + o4 * 4];
      float4 h3 = *(const float4*)&Hs[(jj + 3) * OUT_F + o4 * 4];
      acc0 += pv.x * h0.x; acc1 += pv.x * h0.y; acc2 += pv.x * h0.z; acc3 += pv.x * h0.w;
      acc0 += pv.y * h1.x; acc1 += pv.y * h1.y; acc2 += pv.y * h1.z; acc3 += pv.y * h1.w;
      acc0 += pv.z * h2.x; acc1 += pv.z * h2.y; acc2 += pv.z * h2.z; acc3 += pv.z * h2.w;
      acc0 += pv.w * h3.x; acc1 += pv.w * h3.y; acc2 += pv.w * h3.z; acc3 += pv.w * h3.w;
    }
  }

  // finalize per-row softmax denominators
#pragma unroll
  for (int m = 16; m >= 1; m >>= 1) {
    lsum0 += __shfl_xor(lsum0, m, 64);
    lsum1 += __shfl_xor(lsum1, m, 64);
  }
  if ((t & 31) == 0) { Ls[rp] = lsum0; Ls[16 + rp] = lsum1; }
  __syncthreads();

  float l = Ls[rc];
  float a0 = acc0, a1 = acc1, a2 = acc2, a3 = acc3;
  if (l <= 0.f) {
    // row had zero neighbors: reference softmax degenerates to uniform 1/N
    a0 = a1 = a2 = a3 = 0.f;
    for (int j = 0; j < N; ++j) {
      float4 hv = *(const float4*)&h[(size_t)j * OUT_F + o4 * 4];
      a0 += hv.x; a1 += hv.y; a2 += hv.z; a3 += hv.w;
    }
    l = (float)N;
  }
  float inv = 1.f / l;
  a0 *= inv; a1 *= inv; a2 *= inv; a3 *= inv;
  float4 r4;
  r4.x = a0 > 0.f ? a0 : expm1f(a0);
  r4.y = a1 > 0.f ? a1 : expm1f(a1);
  r4.z = a2 > 0.f ? a2 : expm1f(a2);
  r4.w = a3 > 0.f ? a3 : expm1f(a3);
  *(float4*)&out[(size_t)(i0 + rc) * OUT_F + o4 * 4] = r4;
}

extern "C" void kernel_launch(void* const* d_in, const int* in_sizes, int n_in,
                              void* d_out, int out_size, void* d_ws, size_t ws_size,
                              hipStream_t stream) {
  const float* input = (const float*)d_in[0];
  const int*   adj   = (const int*)d_in[1];
  const float* W     = (const float*)d_in[2];
  const float* a     = (const float*)d_in[3];
  float* out = (float*)d_out;

  float* h  = (float*)d_ws;                    // 8192*64 f32 = 2 MB
  float* f1 = h + (size_t)N * OUT_F;           // 32 KB
  float* f2 = f1 + N;                          // 32 KB
  unsigned* gmax = (unsigned*)(f2 + N);        // 4 B

  (void)hipMemsetAsync(gmax, 0, sizeof(unsigned), stream);
  gat_prep<<<N / 4, 256, 0, stream>>>(input, W, a, h, f1, f2, gmax);
  gat_main<<<N / RB, TB, 0, stream>>>(adj, h, f1, f2, gmax, out);
}

// Round 3
// 310.038 us; speedup vs baseline: 1.2274x; 1.2274x over previous
//
#include <hip/hip_runtime.h>
#include <hip/hip_bf16.h>

#define N 8192
#define IN_F 128
#define OUT_F 64
#define ALPHA 0.2f

#define RB 32        // rows per block (attention kernels)
#define JT 128       // j-tile
#define TB 512       // threads per block (attention kernels)
#define JC 4         // j-chunks (parallel split of the j loop)
#define PSTRIDE 132  // padded P row stride (floats)

typedef int iv4 __attribute__((ext_vector_type(4)));

__device__ __forceinline__ unsigned fmap(float x) {
  unsigned b = __float_as_uint(x);
  return (b & 0x80000000u) ? ~b : (b | 0x80000000u);
}
__device__ __forceinline__ float funmap(unsigned u) {
  unsigned b = (u & 0x80000000u) ? (u & 0x7FFFFFFFu) : ~u;
  return __uint_as_float(b);
}

// Kernel A: h = input @ W ; f1 = h @ a1 ; f2 = h @ a2 ; gmax = max_j f2[j]
// 256 blocks x 32 rows: W staged once per block, 4 waves x 8 row-passes.
__global__ __launch_bounds__(256) void gat_prep(
    const float* __restrict__ input, const float* __restrict__ W,
    const float* __restrict__ a,
    float* __restrict__ h, float* __restrict__ f1, float* __restrict__ f2,
    unsigned* __restrict__ gmax)
{
  __shared__ float Ws[IN_F * OUT_F];   // 32 KB
  __shared__ float ins[RB][IN_F];      // 16 KB
  int t = threadIdx.x;

  const float4* W4 = (const float4*)W;
  float4* Ws4 = (float4*)Ws;
#pragma unroll
  for (int k = 0; k < 8; ++k) Ws4[t + 256 * k] = W4[t + 256 * k];

  int row0 = blockIdx.x * RB;
  const float4* in4 = (const float4*)(input + (size_t)row0 * IN_F);
  float4* ins4 = (float4*)(&ins[0][0]);
#pragma unroll
  for (int k = 0; k < 4; ++k) ins4[t + 256 * k] = in4[t + 256 * k];
  __syncthreads();

  int w = t >> 6;        // wave id
  int o = t & 63;        // output feature
  float a1v = a[o];
  float a2v = a[OUT_F + o];

#pragma unroll
  for (int p = 0; p < 8; ++p) {
    int r = p * 4 + w;
    int i = row0 + r;
    const float4* iv = (const float4*)&ins[r][0];
    float acc = 0.f;
#pragma unroll
    for (int k4 = 0; k4 < 32; ++k4) {
      float4 v = iv[k4];
      acc += v.x * Ws[(k4 * 4 + 0) * OUT_F + o];
      acc += v.y * Ws[(k4 * 4 + 1) * OUT_F + o];
      acc += v.z * Ws[(k4 * 4 + 2) * OUT_F + o];
      acc += v.w * Ws[(k4 * 4 + 3) * OUT_F + o];
    }
    h[(size_t)i * OUT_F + o] = acc;

    float p1 = acc * a1v;
    float p2 = acc * a2v;
#pragma unroll
    for (int m = 32; m >= 1; m >>= 1) {
      p1 += __shfl_xor(p1, m, 64);
      p2 += __shfl_xor(p2, m, 64);
    }
    if (o == 0) {
      f1[i] = p1;
      f2[i] = p2;
      atomicMax(gmax, fmap(p2));
    }
  }
}

// Shared tile body for the attention pass. Computes partial PV numerator and
// partial softmax denominator for rows [i0,i0+RB) over tiles [t0,t1).
// Exactness: shift m_i = lrelu(f1[i] + max_j f2[j]) is a per-row upper bound
// (leaky_relu monotone), so partial sums across j combine linearly.
__device__ __forceinline__ void attn_tiles(
    const int* __restrict__ adj, const float* __restrict__ h,
    const float* __restrict__ f2,
    float* Hs, float* Ps, const float* F1s, const float* Ms,
    int i0, int t0, int t1, int t,
    float& lsum0, float& lsum1,
    float& acc0, float& acc1, float& acc2, float& acc3)
{
  int jq = t & 31;
  int rp = t >> 5;          // 0..15
  int o4 = t & 15;
  int rc = t >> 4;          // 0..31

  for (int jt = t0; jt < t1; ++jt) {
    int j0 = jt * JT;
    __syncthreads();   // protect Hs/Ps from prev-iter readers; F1s/Ms ready

    const float4* Hg4 = (const float4*)(h + (size_t)j0 * OUT_F);
    float4* Hs4 = (float4*)Hs;
#pragma unroll
    for (int k = 0; k < 4; ++k) Hs4[t + TB * k] = Hg4[t + TB * k];

    const float4* f2g4 = (const float4*)(f2 + j0);
#pragma unroll
    for (int p = 0; p < 2; ++p) {
      int r = p * 16 + rp;
      const iv4* arow = (const iv4*)(adj + (size_t)(i0 + r) * N + j0);
      iv4 av = __builtin_nontemporal_load(&arow[jq]);
      float4 fv = f2g4[jq];
      float f1v = F1s[r], mv = Ms[r];
      float4 pv;
      float e;
      e = f1v + fv.x; e = e > 0.f ? e : ALPHA * e; pv.x = (av.x > 0) ? __expf(e - mv) : 0.f;
      e = f1v + fv.y; e = e > 0.f ? e : ALPHA * e; pv.y = (av.y > 0) ? __expf(e - mv) : 0.f;
      e = f1v + fv.z; e = e > 0.f ? e : ALPHA * e; pv.z = (av.z > 0) ? __expf(e - mv) : 0.f;
      e = f1v + fv.w; e = e > 0.f ? e : ALPHA * e; pv.w = (av.w > 0) ? __expf(e - mv) : 0.f;
      *(float4*)&Ps[r * PSTRIDE + jq * 4] = pv;
      float s = pv.x + pv.y + pv.z + pv.w;
      if (p == 0) lsum0 += s; else lsum1 += s;
    }
    __syncthreads();

    const float* prow = &Ps[rc * PSTRIDE];
#pragma unroll 8
    for (int jj = 0; jj < JT; jj += 4) {
      float4 pv = *(const float4*)&prow[jj];
      float4 h0 = *(const float4*)&Hs[(jj + 0) * OUT_F + o4 * 4];
      float4 h1 = *(const float4*)&Hs[(jj + 1) * OUT_F + o4 * 4];
      float4 h2 = *(const float4*)&Hs[(jj + 2) * OUT_F + o4 * 4];
      float4 h3 = *(const float4*)&Hs[(jj + 3) * OUT_F + o4 * 4];
      acc0 += pv.x * h0.x; acc1 += pv.x * h0.y; acc2 += pv.x * h0.z; acc3 += pv.x * h0.w;
      acc0 += pv.y * h1.x; acc1 += pv.y * h1.y; acc2 += pv.y * h1.z; acc3 += pv.y * h1.w;
      acc0 += pv.z * h2.x; acc1 += pv.z * h2.y; acc2 += pv.z * h2.z; acc3 += pv.z * h2.w;
      acc0 += pv.w * h3.x; acc1 += pv.w * h3.y; acc2 += pv.w * h3.z; acc3 += pv.w * h3.w;
    }
  }
}

// Kernel B (split): partial attention over one j-chunk.
// grid = JC * (N/RB) blocks; block (ib, jc) does rows [ib*RB,..) over
// tiles [jc*T, (jc+1)*T). Writes num[jc][i][o], den[jc][i].
__global__ __launch_bounds__(TB) void gat_part(
    const int* __restrict__ adj, const float* __restrict__ h,
    const float* __restrict__ f1, const float* __restrict__ f2,
    const unsigned* __restrict__ gmaxp,
    float* __restrict__ num, float* __restrict__ den)
{
  __shared__ float Hs[JT * OUT_F];
  __shared__ float Ps[RB * PSTRIDE];
  __shared__ float Ls[RB];
  __shared__ float Ms[RB];
  __shared__ float F1s[RB];

  int t = threadIdx.x;
  int bid = blockIdx.x;
  int ib = bid & (N / RB - 1);
  int jc = bid >> 8;           // N/RB == 256
  int i0 = ib * RB;

  if (t < RB) {
    float gmax = funmap(*gmaxp);
    float f1v = f1[i0 + t];
    F1s[t] = f1v;
    float e = f1v + gmax;
    Ms[t] = e > 0.f ? e : ALPHA * e;
  }

  float lsum0 = 0.f, lsum1 = 0.f;
  float acc0 = 0.f, acc1 = 0.f, acc2 = 0.f, acc3 = 0.f;
  const int T = N / JT / JC;   // 16 tiles per chunk

  attn_tiles(adj, h, f2, Hs, Ps, F1s, Ms, i0, jc * T, (jc + 1) * T, t,
             lsum0, lsum1, acc0, acc1, acc2, acc3);

#pragma unroll
  for (int m = 16; m >= 1; m >>= 1) {
    lsum0 += __shfl_xor(lsum0, m, 64);
    lsum1 += __shfl_xor(lsum1, m, 64);
  }
  int rp = t >> 5;
  if ((t & 31) == 0 && rp < 16) { Ls[rp] = lsum0; Ls[16 + rp] = lsum1; }
  __syncthreads();

  int o4 = t & 15;
  int rc = t >> 4;
  float4 r4; r4.x = acc0; r4.y = acc1; r4.z = acc2; r4.w = acc3;
  *(float4*)&num[(((size_t)jc * N) + i0 + rc) * OUT_F + o4 * 4] = r4;
  if (t < RB) den[(size_t)jc * N + i0 + t] = Ls[t];
}

// Kernel C: combine partials, normalize, ELU. 512 blocks x 16 rows.
__global__ __launch_bounds__(256) void gat_reduce(
    const float* __restrict__ h, const float* __restrict__ num,
    const float* __restrict__ den, float* __restrict__ out)
{
  int t = threadIdx.x;
  int i = blockIdx.x * 16 + (t >> 4);
  int o4 = t & 15;

  float d = 0.f;
#pragma unroll
  for (int c = 0; c < JC; ++c) d += den[(size_t)c * N + i];

  float a0 = 0.f, a1 = 0.f, a2 = 0.f, a3 = 0.f;
#pragma unroll
  for (int c = 0; c < JC; ++c) {
    float4 v = *(const float4*)&num[(((size_t)c * N) + i) * OUT_F + o4 * 4];
    a0 += v.x; a1 += v.y; a2 += v.z; a3 += v.w;
  }

  if (d <= 0.f) {
    // row with zero neighbors: softmax degenerates to uniform 1/N
    a0 = a1 = a2 = a3 = 0.f;
    for (int j = 0; j < N; ++j) {
      float4 hv = *(const float4*)&h[(size_t)j * OUT_F + o4 * 4];
      a0 += hv.x; a1 += hv.y; a2 += hv.z; a3 += hv.w;
    }
    d = (float)N;
  }
  float inv = 1.f / d;
  a0 *= inv; a1 *= inv; a2 *= inv; a3 *= inv;
  float4 r4;
  r4.x = a0 > 0.f ? a0 : expm1f(a0);
  r4.y = a1 > 0.f ? a1 : expm1f(a1);
  r4.z = a2 > 0.f ? a2 : expm1f(a2);
  r4.w = a3 > 0.f ? a3 : expm1f(a3);
  *(float4*)&out[(size_t)i * OUT_F + o4 * 4] = r4;
}

// Fallback single-pass kernel (used if ws too small for partials).
__global__ __launch_bounds__(TB) void gat_main(
    const int* __restrict__ adj, const float* __restrict__ h,
    const float* __restrict__ f1, const float* __restrict__ f2,
    const unsigned* __restrict__ gmaxp, float* __restrict__ out)
{
  __shared__ float Hs[JT * OUT_F];
  __shared__ float Ps[RB * PSTRIDE];
  __shared__ float Ls[RB];
  __shared__ float Ms[RB];
  __shared__ float F1s[RB];

  int t = threadIdx.x;
  int i0 = blockIdx.x * RB;

  if (t < RB) {
    float gmax = funmap(*gmaxp);
    float f1v = f1[i0 + t];
    F1s[t] = f1v;
    float e = f1v + gmax;
    Ms[t] = e > 0.f ? e : ALPHA * e;
  }

  float lsum0 = 0.f, lsum1 = 0.f;
  float acc0 = 0.f, acc1 = 0.f, acc2 = 0.f, acc3 = 0.f;

  attn_tiles(adj, h, f2, Hs, Ps, F1s, Ms, i0, 0, N / JT, t,
             lsum0, lsum1, acc0, acc1, acc2, acc3);

#pragma unroll
  for (int m = 16; m >= 1; m >>= 1) {
    lsum0 += __shfl_xor(lsum0, m, 64);
    lsum1 += __shfl_xor(lsum1, m, 64);
  }
  int rp = t >> 5;
  if ((t & 31) == 0 && rp < 16) { Ls[rp] = lsum0; Ls[16 + rp] = lsum1; }
  __syncthreads();

  int o4 = t & 15;
  int rc = t >> 4;
  float l = Ls[rc];
  float a0 = acc0, a1 = acc1, a2 = acc2, a3 = acc3;
  if (l <= 0.f) {
    a0 = a1 = a2 = a3 = 0.f;
    for (int j = 0; j < N; ++j) {
      float4 hv = *(const float4*)&h[(size_t)j * OUT_F + o4 * 4];
      a0 += hv.x; a1 += hv.y; a2 += hv.z; a3 += hv.w;
    }
    l = (float)N;
  }
  float inv = 1.f / l;
  a0 *= inv; a1 *= inv; a2 *= inv; a3 *= inv;
  float4 r4;
  r4.x = a0 > 0.f ? a0 : expm1f(a0);
  r4.y = a1 > 0.f ? a1 : expm1f(a1);
  r4.z = a2 > 0.f ? a2 : expm1f(a2);
  r4.w = a3 > 0.f ? a3 : expm1f(a3);
  *(float4*)&out[(size_t)(i0 + rc) * OUT_F + o4 * 4] = r4;
}

extern "C" void kernel_launch(void* const* d_in, const int* in_sizes, int n_in,
                              void* d_out, int out_size, void* d_ws, size_t ws_size,
                              hipStream_t stream) {
  const float* input = (const float*)d_in[0];
  const int*   adj   = (const int*)d_in[1];
  const float* W     = (const float*)d_in[2];
  const float* a     = (const float*)d_in[3];
  float* out = (float*)d_out;

  float* ws = (float*)d_ws;
  float* h  = ws;                              // N*64 f32 = 2 MB
  float* f1 = h + (size_t)N * OUT_F;           // N
  float* f2 = f1 + N;                          // N
  unsigned* gmax = (unsigned*)(f2 + N);        // 1
  float* den = f2 + N + 4;                     // JC*N
  float* num = den + (size_t)JC * N;           // JC*N*64 = 8 MB
  size_t need = (size_t)(num + (size_t)JC * N * OUT_F - ws) * sizeof(float);

  (void)hipMemsetAsync(gmax, 0, sizeof(unsigned), stream);
  gat_prep<<<N / RB, 256, 0, stream>>>(input, W, a, h, f1, f2, gmax);

  if (ws_size >= need) {
    gat_part<<<JC * (N / RB), TB, 0, stream>>>(adj, h, f1, f2, gmax, num, den);
    gat_reduce<<<N / 16, 256, 0, stream>>>(h, num, den, out);
  } else {
    gat_main<<<N / RB, TB, 0, stream>>>(adj, h, f1, f2, gmax, out);
  }
}

// Round 4
// 212.001 us; speedup vs baseline: 1.7949x; 1.4624x over previous
//
#include <hip/hip_runtime.h>

#define N 8192
#define IN_F 128
#define OUT_F 64
#define ALPHA 0.2f

#define RB 32        // rows per block (attention)
#define JT 128       // j-tile (K per LDS stage)
#define TB 512       // threads per block (attention)
#define JC 4         // j-chunks

typedef int          iv4    __attribute__((ext_vector_type(4)));
typedef unsigned int uv4    __attribute__((ext_vector_type(4)));
typedef unsigned int uv2    __attribute__((ext_vector_type(2)));
typedef __bf16       bf16x8 __attribute__((ext_vector_type(8)));
typedef float        f32x4  __attribute__((ext_vector_type(4)));

__device__ __forceinline__ unsigned fmap(float x) {
  unsigned b = __float_as_uint(x);
  return (b & 0x80000000u) ? ~b : (b | 0x80000000u);
}
__device__ __forceinline__ float funmap(unsigned u) {
  unsigned b = (u & 0x80000000u) ? (u & 0x7FFFFFFFu) : ~u;
  return __uint_as_float(b);
}
__device__ __forceinline__ unsigned short f2bf(float x) {  // RNE f32->bf16
  unsigned u = __float_as_uint(x);
  u += 0x7fffu + ((u >> 16) & 1u);
  return (unsigned short)(u >> 16);
}
__device__ __forceinline__ float bf2f(unsigned short b) {
  return __uint_as_float(((unsigned)b) << 16);
}

// Kernel A: h = input @ W ; f1 = h@a1 ; f2 = h@a2 ; gmax = max_j f2[j].
// Writes h TRANSPOSED as bf16: ht[o][i] (o-major) for MFMA B staging.
// 1024 blocks x 8 rows.
__global__ __launch_bounds__(256) void gat_prep(
    const float* __restrict__ input, const float* __restrict__ W,
    const float* __restrict__ a,
    unsigned short* __restrict__ ht, float* __restrict__ f1,
    float* __restrict__ f2, unsigned* __restrict__ gmax)
{
  __shared__ float Ws[IN_F * OUT_F];                    // 32 KB
  __shared__ float ins[8][IN_F];                        // 4 KB
  __shared__ __align__(16) unsigned short Hts[OUT_F][8];
  int t = threadIdx.x;

  const float4* W4 = (const float4*)W;
  float4* Ws4 = (float4*)Ws;
#pragma unroll
  for (int k = 0; k < 8; ++k) Ws4[t + 256 * k] = W4[t + 256 * k];

  int row0 = blockIdx.x * 8;
  const float4* in4 = (const float4*)(input + (size_t)row0 * IN_F);
  ((float4*)&ins[0][0])[t] = in4[t];
  __syncthreads();

  int w = t >> 6, o = t & 63;
  float a1v = a[o], a2v = a[OUT_F + o];

#pragma unroll
  for (int p = 0; p < 2; ++p) {
    int r = p * 4 + w;
    int i = row0 + r;
    const float4* iv = (const float4*)&ins[r][0];
    float acc = 0.f;
#pragma unroll
    for (int k4 = 0; k4 < 32; ++k4) {
      float4 v = iv[k4];
      acc += v.x * Ws[(k4 * 4 + 0) * OUT_F + o];
      acc += v.y * Ws[(k4 * 4 + 1) * OUT_F + o];
      acc += v.z * Ws[(k4 * 4 + 2) * OUT_F + o];
      acc += v.w * Ws[(k4 * 4 + 3) * OUT_F + o];
    }
    Hts[o][r] = f2bf(acc);
    float p1 = acc * a1v, p2 = acc * a2v;
#pragma unroll
    for (int m = 32; m >= 1; m >>= 1) {
      p1 += __shfl_xor(p1, m, 64);
      p2 += __shfl_xor(p2, m, 64);
    }
    if (o == 0) {
      f1[i] = p1;
      f2[i] = p2;
      atomicMax(gmax, fmap(p2));
    }
  }
  __syncthreads();
  if (t < 64) {
    uv4 v = *(const uv4*)&Hts[t][0];
    *(uv4*)&ht[(size_t)t * N + row0] = v;   // 8 bf16 = 16 B, coalesced-ish
  }
}

// Kernel B: per j-chunk partial masked-softmax attention with MFMA PV.
// P tile (32x128) computed on VALU, stored bf16 into swizzled LDS (A-frag);
// Ht tile (64 features x 128 j) staged bf16 swizzled (B-frag).
// 8 waves = 2(m) x 4(n) 16x16 C-tiles; K=128 per tile = 4 mfma/wave.
// Shift m_i = lrelu(f1[i]+gmax) is an exact upper bound (lrelu monotone),
// so chunk partial sums combine linearly.
__global__ __launch_bounds__(TB) void gat_part(
    const int* __restrict__ adj, const unsigned short* __restrict__ ht,
    const float* __restrict__ f1, const float* __restrict__ f2,
    const unsigned* __restrict__ gmaxp,
    float* __restrict__ num, float* __restrict__ den, int jcc)
{
  __shared__ __align__(16) unsigned short HtS[OUT_F * JT]; // [o][j] swz, 16 KB
  __shared__ __align__(16) unsigned short PS[RB * JT];     // [r][k] swz, 8 KB
  __shared__ float F1s[RB];
  __shared__ float Ms[RB];

  int t = threadIdx.x;
  int ib = blockIdx.x & 255;        // N/RB == 256
  int jc = blockIdx.x >> 8;
  int i0 = ib * RB;
  int T = (N / JT) / jcc;

  if (t < RB) {
    float gmaxv = funmap(*gmaxp);
    float f1v = f1[i0 + t];
    F1s[t] = f1v;
    float e = f1v + gmaxv;
    Ms[t] = e > 0.f ? e : ALPHA * e;
  }
  __syncthreads();

  // P-compute identity: 32 lanes (jq) x 16 row-slots (rp), 2 passes
  int jq = t & 31, rp = t >> 5;
  // Ht staging identity: feature so, j-chunk sc
  int so = t >> 3, sc = t & 7;
  // MFMA identity: wave w -> (m0,n0) subtile
  int w = t >> 6, l = t & 63;
  int m0 = (w & 1) * 16, n0 = (w >> 1) * 16;
  int arow = m0 + (l & 15);
  int bcol = n0 + (l & 15);
  int kg = (l >> 4) * 16;           // byte offset of lane's 8-elem k-group
  unsigned aswz = (unsigned)((arow & 7) << 4);
  unsigned bswz = (unsigned)((bcol & 7) << 4);

  float lsum0 = 0.f, lsum1 = 0.f;
  f32x4 acc = {0.f, 0.f, 0.f, 0.f};

  char* PSb = (char*)PS;
  char* HtSb = (char*)HtS;

  for (int jt = jc * T; jt < (jc + 1) * T; ++jt) {
    int j0 = jt * JT;

    // stage Ht tile: 2 x 16 B per thread, swizzled byte ^= (o&7)<<4
    {
      const unsigned short* src = ht + (size_t)so * N + j0 + sc * 8;
      uv4 h0 = *(const uv4*)(src);
      uv4 h1 = *(const uv4*)(src + 64);
      unsigned swz = (unsigned)((so & 7) << 4);
      *(uv4*)(HtSb + (((unsigned)(so * 256 + sc * 16)) ^ swz)) = h0;
      *(uv4*)(HtSb + (((unsigned)(so * 256 + 128 + sc * 16)) ^ swz)) = h1;
    }

    // P tile: p = adj ? exp(lrelu(f1+f2) - m) : 0, rounded to bf16
    const float4* f2g4 = (const float4*)(f2 + j0);
#pragma unroll
    for (int p = 0; p < 2; ++p) {
      int r = p * 16 + rp;
      const iv4* arowp = (const iv4*)(adj + (size_t)(i0 + r) * N + j0);
      iv4 av = __builtin_nontemporal_load(&arowp[jq]);
      float4 fv = f2g4[jq];
      float f1v = F1s[r], mv = Ms[r];
      float e; float4 pv;
      e = f1v + fv.x; e = e > 0.f ? e : ALPHA * e; pv.x = (av.x > 0) ? __expf(e - mv) : 0.f;
      e = f1v + fv.y; e = e > 0.f ? e : ALPHA * e; pv.y = (av.y > 0) ? __expf(e - mv) : 0.f;
      e = f1v + fv.z; e = e > 0.f ? e : ALPHA * e; pv.z = (av.z > 0) ? __expf(e - mv) : 0.f;
      e = f1v + fv.w; e = e > 0.f ? e : ALPHA * e; pv.w = (av.w > 0) ? __expf(e - mv) : 0.f;
      unsigned short b0 = f2bf(pv.x), b1 = f2bf(pv.y), b2 = f2bf(pv.z), b3 = f2bf(pv.w);
      // denominator from the ROUNDED values (consistent with MFMA numerator)
      float s = (bf2f(b0) + bf2f(b1)) + (bf2f(b2) + bf2f(b3));
      uv2 w2;
      w2.x = (unsigned)b0 | ((unsigned)b1 << 16);
      w2.y = (unsigned)b2 | ((unsigned)b3 << 16);
      *(uv2*)(PSb + (((unsigned)(r * 256 + jq * 8)) ^ ((unsigned)((r & 7) << 4)))) = w2;
      if (p == 0) lsum0 += s; else lsum1 += s;
    }
    __syncthreads();   // LDS tiles ready

    // MFMA: acc += P[m0+..][k] * Ht[n0+..][k]^T over K=128
#pragma unroll
    for (int ks = 0; ks < 4; ++ks) {
      bf16x8 a8 = __builtin_bit_cast(bf16x8,
          *(const uv4*)(PSb + (((unsigned)(arow * 256 + ks * 64 + kg)) ^ aswz)));
      bf16x8 b8 = __builtin_bit_cast(bf16x8,
          *(const uv4*)(HtSb + (((unsigned)(bcol * 256 + ks * 64 + kg)) ^ bswz)));
      acc = __builtin_amdgcn_mfma_f32_16x16x32_bf16(a8, b8, acc, 0, 0, 0);
    }
    __syncthreads();   // protect tiles from next iteration's writes
  }

  // denominator: reduce over 32 jq lanes (within each half-wave)
#pragma unroll
  for (int m = 16; m >= 1; m >>= 1) {
    lsum0 += __shfl_xor(lsum0, m, 64);
    lsum1 += __shfl_xor(lsum1, m, 64);
  }
  if ((t & 31) == 0) {
    den[(size_t)jc * N + i0 + rp] = lsum0;
    den[(size_t)jc * N + i0 + rp + 16] = lsum1;
  }

  // numerator: C/D layout col=l&15, row=(l>>4)*4+reg  [m89-verified]
  int crow = i0 + m0 + ((l >> 4) << 2);
  float* np = num + ((size_t)jc * N + crow) * OUT_F + n0 + (l & 15);
  np[0 * OUT_F] = acc[0];
  np[1 * OUT_F] = acc[1];
  np[2 * OUT_F] = acc[2];
  np[3 * OUT_F] = acc[3];
}

// Kernel C: combine chunk partials, normalize, ELU. 512 blocks x 16 rows.
__global__ __launch_bounds__(256) void gat_reduce(
    const unsigned short* __restrict__ ht, const float* __restrict__ num,
    const float* __restrict__ den, float* __restrict__ out, int jcc)
{
  int t = threadIdx.x;
  int i = blockIdx.x * 16 + (t >> 4);
  int o4 = t & 15;

  float d = 0.f;
  for (int c = 0; c < jcc; ++c) d += den[(size_t)c * N + i];

  float a0 = 0.f, a1 = 0.f, a2 = 0.f, a3 = 0.f;
  for (int c = 0; c < jcc; ++c) {
    float4 v = *(const float4*)&num[(((size_t)c * N) + i) * OUT_F + o4 * 4];
    a0 += v.x; a1 += v.y; a2 += v.z; a3 += v.w;
  }

  if (d <= 0.f) {
    // row with zero neighbors: softmax degenerates to uniform 1/N
    a0 = a1 = a2 = a3 = 0.f;
    for (int j = 0; j < N; ++j) {
      a0 += bf2f(ht[(size_t)(o4 * 4 + 0) * N + j]);
      a1 += bf2f(ht[(size_t)(o4 * 4 + 1) * N + j]);
      a2 += bf2f(ht[(size_t)(o4 * 4 + 2) * N + j]);
      a3 += bf2f(ht[(size_t)(o4 * 4 + 3) * N + j]);
    }
    d = (float)N;
  }
  float inv = 1.f / d;
  a0 *= inv; a1 *= inv; a2 *= inv; a3 *= inv;
  float4 r4;
  r4.x = a0 > 0.f ? a0 : expm1f(a0);
  r4.y = a1 > 0.f ? a1 : expm1f(a1);
  r4.z = a2 > 0.f ? a2 : expm1f(a2);
  r4.w = a3 > 0.f ? a3 : expm1f(a3);
  *(float4*)&out[(size_t)i * OUT_F + o4 * 4] = r4;
}

extern "C" void kernel_launch(void* const* d_in, const int* in_sizes, int n_in,
                              void* d_out, int out_size, void* d_ws, size_t ws_size,
                              hipStream_t stream) {
  const float* input = (const float*)d_in[0];
  const int*   adj   = (const int*)d_in[1];
  const float* W     = (const float*)d_in[2];
  const float* a     = (const float*)d_in[3];
  float* out = (float*)d_out;

  unsigned short* ht = (unsigned short*)d_ws;        // N*64 bf16 = 1 MB
  float* f1 = (float*)(ht + (size_t)N * OUT_F);      // N
  float* f2 = f1 + N;                                // N
  unsigned* gmax = (unsigned*)(f2 + N);              // 1 (+pad 3)
  float* den = (float*)(gmax + 4);                   // JC*N
  float* num = den + (size_t)JC * N;                 // JC*N*64 = 8 MB
  size_t need = (size_t)((char*)(num + (size_t)JC * N * OUT_F) - (char*)d_ws);

  int jcc = (ws_size >= need) ? JC : 1;

  (void)hipMemsetAsync(gmax, 0, sizeof(unsigned), stream);
  gat_prep<<<N / 8, 256, 0, stream>>>(input, W, a, ht, f1, f2, gmax);
  gat_part<<<jcc * (N / RB), TB, 0, stream>>>(adj, ht, f1, f2, gmax, num, den, jcc);
  gat_reduce<<<N / 16, 256, 0, stream>>>(ht, num, den, out, jcc);
}

// Round 5
// 84.832 us; speedup vs baseline: 4.4857x; 2.4991x over previous
//
#include <hip/hip_runtime.h>

#define N 8192
#define IN_F 128
#define OUT_F 64
#define ALPHA 0.2f

#define RB 32        // rows per block (attention)
#define JT 128       // j-tile (K per LDS stage)
#define TB 512       // threads per block (attention)
#define JC 8         // j-chunks

typedef int          iv4    __attribute__((ext_vector_type(4)));
typedef unsigned int uv4    __attribute__((ext_vector_type(4)));
typedef unsigned int uv2    __attribute__((ext_vector_type(2)));
typedef __bf16       bf16x8 __attribute__((ext_vector_type(8)));
typedef float        f32x4  __attribute__((ext_vector_type(4)));

__device__ __forceinline__ unsigned short f2bf(float x) {  // RNE f32->bf16
  unsigned u = __float_as_uint(x);
  u += 0x7fffu + ((u >> 16) & 1u);
  return (unsigned short)(u >> 16);
}
__device__ __forceinline__ float bf2f(unsigned short b) {
  return __uint_as_float(((unsigned)b) << 16);
}

// Kernel A: h = input @ W ; f1 = h@a1 ; f2 = h@a2 ; bmax[b] = max f2 in block.
// Writes h TRANSPOSED as bf16: ht[o][i]. 1024 blocks x 8 rows.
__global__ __launch_bounds__(256) void gat_prep(
    const float* __restrict__ input, const float* __restrict__ W,
    const float* __restrict__ a,
    unsigned short* __restrict__ ht, float* __restrict__ f1,
    float* __restrict__ f2, float* __restrict__ bmax)
{
  __shared__ float Ws[IN_F * OUT_F];                    // 32 KB
  __shared__ float ins[8][IN_F];                        // 4 KB
  __shared__ __align__(16) unsigned short Hts[OUT_F][8];
  __shared__ float bm[4];
  int t = threadIdx.x;

  const float4* W4 = (const float4*)W;
  float4* Ws4 = (float4*)Ws;
#pragma unroll
  for (int k = 0; k < 8; ++k) Ws4[t + 256 * k] = W4[t + 256 * k];

  int row0 = blockIdx.x * 8;
  const float4* in4 = (const float4*)(input + (size_t)row0 * IN_F);
  ((float4*)&ins[0][0])[t] = in4[t];
  __syncthreads();

  int w = t >> 6, o = t & 63;
  float a1v = a[o], a2v = a[OUT_F + o];
  float pmax = -3.4e38f;

#pragma unroll
  for (int p = 0; p < 2; ++p) {
    int r = p * 4 + w;
    int i = row0 + r;
    const float4* iv = (const float4*)&ins[r][0];
    float acc = 0.f;
#pragma unroll
    for (int k4 = 0; k4 < 32; ++k4) {
      float4 v = iv[k4];
      acc += v.x * Ws[(k4 * 4 + 0) * OUT_F + o];
      acc += v.y * Ws[(k4 * 4 + 1) * OUT_F + o];
      acc += v.z * Ws[(k4 * 4 + 2) * OUT_F + o];
      acc += v.w * Ws[(k4 * 4 + 3) * OUT_F + o];
    }
    Hts[o][r] = f2bf(acc);
    float p1 = acc * a1v, p2 = acc * a2v;
#pragma unroll
    for (int m = 32; m >= 1; m >>= 1) {
      p1 += __shfl_xor(p1, m, 64);
      p2 += __shfl_xor(p2, m, 64);
    }
    pmax = fmaxf(pmax, p2);      // butterfly left p2 in every lane
    if (o == 0) {
      f1[i] = p1;
      f2[i] = p2;
    }
  }
  if (o == 0) bm[w] = pmax;
  __syncthreads();
  if (t < 64) {
    uv4 v = *(const uv4*)&Hts[t][0];
    *(uv4*)&ht[(size_t)t * N + row0] = v;
  }
  if (t == 0)
    bmax[blockIdx.x] = fmaxf(fmaxf(bm[0], bm[1]), fmaxf(bm[2], bm[3]));
}

// Kernel B: per j-chunk partial masked-softmax attention with MFMA PV.
// Double-buffered LDS tiles, ONE barrier per tile, adj prefetched one tile
// ahead. Shift m_i = lrelu(f1[i]+gmax) is an exact upper bound (lrelu
// monotone), so chunk partial sums combine linearly.
__global__ __launch_bounds__(TB) void gat_part(
    const int* __restrict__ adj, const unsigned short* __restrict__ ht,
    const float* __restrict__ f1, const float* __restrict__ f2,
    const float* __restrict__ bmax,
    float* __restrict__ num, float* __restrict__ den, int jcc)
{
  __shared__ __align__(16) unsigned short HtS[2][OUT_F * JT]; // 2x16 KB
  __shared__ __align__(16) unsigned short PS[2][RB * JT];     // 2x8 KB
  __shared__ float F1s[RB];
  __shared__ float Ms[RB];
  __shared__ float gm[8];

  int t = threadIdx.x;
  int ib = blockIdx.x & 255;        // N/RB == 256
  int jc = blockIdx.x >> 8;
  int i0 = ib * RB;
  int T = (N / JT) / jcc;

  // global max of f2 from per-block maxima (1024 entries)
  {
    float v = fmaxf(bmax[t], bmax[t + 512]);
#pragma unroll
    for (int m = 32; m >= 1; m >>= 1) v = fmaxf(v, __shfl_xor(v, m, 64));
    if ((t & 63) == 0) gm[t >> 6] = v;
  }
  __syncthreads();
  if (t < RB) {
    float g = gm[0];
#pragma unroll
    for (int k = 1; k < 8; ++k) g = fmaxf(g, gm[k]);
    float f1v = f1[i0 + t];
    F1s[t] = f1v;
    float e = f1v + g;
    Ms[t] = e > 0.f ? e : ALPHA * e;
  }

  // P-compute identity: 32 lanes (jq) x 16 row-slots (rp), 2 row passes
  int jq = t & 31, rp = t >> 5;
  // Ht staging identity: feature so, j-chunk sc
  int so = t >> 3, sc = t & 7;
  // MFMA identity: wave w -> (m0,n0) subtile
  int w = t >> 6, l = t & 63;
  int m0 = (w & 1) * 16, n0 = (w >> 1) * 16;
  int arow = m0 + (l & 15);
  int bcol = n0 + (l & 15);
  int kg = (l >> 4) * 16;
  unsigned aswz = (unsigned)((arow & 7) << 4);
  unsigned bswz = (unsigned)((bcol & 7) << 4);
  unsigned sswz = (unsigned)((so & 7) << 4);
  unsigned pswz = (unsigned)((rp & 7) << 4);   // rows rp and rp+16 share (r&7)

  float lsum0 = 0.f, lsum1 = 0.f;
  f32x4 acc = {0.f, 0.f, 0.f, 0.f};

  int jt0 = jc * T, jt1 = (jc + 1) * T;
  const int* arow0 = adj + (size_t)(i0 + rp) * N;
  const int* arow1 = adj + (size_t)(i0 + rp + 16) * N;

  // prologue: prefetch first adj tile
  iv4 av0 = __builtin_nontemporal_load((const iv4*)(arow0 + jt0 * JT) + jq);
  iv4 av1 = __builtin_nontemporal_load((const iv4*)(arow1 + jt0 * JT) + jq);
  __syncthreads();   // F1s/Ms ready

  int buf = 0;
  for (int jt = jt0; jt < jt1; ++jt) {
    int j0 = jt * JT;
    char* HtSb = (char*)&HtS[buf][0];
    char* PSb = (char*)&PS[buf][0];

    // stage Ht tile (global, L2-hot), swizzled byte ^= (o&7)<<4
    {
      const unsigned short* src = ht + (size_t)so * N + j0 + sc * 8;
      uv4 h0 = *(const uv4*)(src);
      uv4 h1 = *(const uv4*)(src + 64);
      *(uv4*)(HtSb + (((unsigned)(so * 256 + sc * 16)) ^ sswz)) = h0;
      *(uv4*)(HtSb + (((unsigned)(so * 256 + 128 + sc * 16)) ^ sswz)) = h1;
    }

    // P tile from prefetched adj: p = adj ? exp(lrelu(f1+f2)-m) : 0 (bf16)
    {
      float4 fv = *(const float4*)(f2 + j0 + jq * 4);
      float e; float4 pv; uv2 w2;

      float f1v = F1s[rp], mv = Ms[rp];
      e = f1v + fv.x; e = e > 0.f ? e : ALPHA * e; pv.x = (av0.x > 0) ? __expf(e - mv) : 0.f;
      e = f1v + fv.y; e = e > 0.f ? e : ALPHA * e; pv.y = (av0.y > 0) ? __expf(e - mv) : 0.f;
      e = f1v + fv.z; e = e > 0.f ? e : ALPHA * e; pv.z = (av0.z > 0) ? __expf(e - mv) : 0.f;
      e = f1v + fv.w; e = e > 0.f ? e : ALPHA * e; pv.w = (av0.w > 0) ? __expf(e - mv) : 0.f;
      unsigned short b0 = f2bf(pv.x), b1 = f2bf(pv.y), b2 = f2bf(pv.z), b3 = f2bf(pv.w);
      lsum0 += (bf2f(b0) + bf2f(b1)) + (bf2f(b2) + bf2f(b3));
      w2.x = (unsigned)b0 | ((unsigned)b1 << 16);
      w2.y = (unsigned)b2 | ((unsigned)b3 << 16);
      *(uv2*)(PSb + (((unsigned)(rp * 256 + jq * 8)) ^ pswz)) = w2;

      f1v = F1s[rp + 16]; mv = Ms[rp + 16];
      e = f1v + fv.x; e = e > 0.f ? e : ALPHA * e; pv.x = (av1.x > 0) ? __expf(e - mv) : 0.f;
      e = f1v + fv.y; e = e > 0.f ? e : ALPHA * e; pv.y = (av1.y > 0) ? __expf(e - mv) : 0.f;
      e = f1v + fv.z; e = e > 0.f ? e : ALPHA * e; pv.z = (av1.z > 0) ? __expf(e - mv) : 0.f;
      e = f1v + fv.w; e = e > 0.f ? e : ALPHA * e; pv.w = (av1.w > 0) ? __expf(e - mv) : 0.f;
      b0 = f2bf(pv.x); b1 = f2bf(pv.y); b2 = f2bf(pv.z); b3 = f2bf(pv.w);
      lsum1 += (bf2f(b0) + bf2f(b1)) + (bf2f(b2) + bf2f(b3));
      w2.x = (unsigned)b0 | ((unsigned)b1 << 16);
      w2.y = (unsigned)b2 | ((unsigned)b3 << 16);
      *(uv2*)(PSb + (((unsigned)((rp + 16) * 256 + jq * 8)) ^ pswz)) = w2;
    }

    // prefetch next adj tile (lands during sync + MFMA)
    if (jt + 1 < jt1) {
      av0 = __builtin_nontemporal_load((const iv4*)(arow0 + (jt + 1) * JT) + jq);
      av1 = __builtin_nontemporal_load((const iv4*)(arow1 + (jt + 1) * JT) + jq);
    }
    __syncthreads();   // buf tiles ready (single barrier; dbuf protects reuse)

    // MFMA: acc += P[m0+..][k] * Ht[n0+..][k]^T over K=128
#pragma unroll
    for (int ks = 0; ks < 4; ++ks) {
      bf16x8 a8 = __builtin_bit_cast(bf16x8,
          *(const uv4*)(PSb + (((unsigned)(arow * 256 + ks * 64 + kg)) ^ aswz)));
      bf16x8 b8 = __builtin_bit_cast(bf16x8,
          *(const uv4*)(HtSb + (((unsigned)(bcol * 256 + ks * 64 + kg)) ^ bswz)));
      acc = __builtin_amdgcn_mfma_f32_16x16x32_bf16(a8, b8, acc, 0, 0, 0);
    }
    buf ^= 1;
  }

  // denominator: reduce over 32 jq lanes (within each half-wave)
#pragma unroll
  for (int m = 16; m >= 1; m >>= 1) {
    lsum0 += __shfl_xor(lsum0, m, 64);
    lsum1 += __shfl_xor(lsum1, m, 64);
  }
  if ((t & 31) == 0) {
    den[(size_t)jc * N + i0 + rp] = lsum0;
    den[(size_t)jc * N + i0 + rp + 16] = lsum1;
  }

  // numerator: C/D layout col=l&15, row=(l>>4)*4+reg  [m89-verified]
  int crow = i0 + m0 + ((l >> 4) << 2);
  float* np = num + ((size_t)jc * N + crow) * OUT_F + n0 + (l & 15);
  np[0 * OUT_F] = acc[0];
  np[1 * OUT_F] = acc[1];
  np[2 * OUT_F] = acc[2];
  np[3 * OUT_F] = acc[3];
}

// Kernel C: combine chunk partials, normalize, ELU. 512 blocks x 16 rows.
__global__ __launch_bounds__(256) void gat_reduce(
    const unsigned short* __restrict__ ht, const float* __restrict__ num,
    const float* __restrict__ den, float* __restrict__ out, int jcc)
{
  int t = threadIdx.x;
  int i = blockIdx.x * 16 + (t >> 4);
  int o4 = t & 15;

  float d = 0.f;
  for (int c = 0; c < jcc; ++c) d += den[(size_t)c * N + i];

  float a0 = 0.f, a1 = 0.f, a2 = 0.f, a3 = 0.f;
  for (int c = 0; c < jcc; ++c) {
    float4 v = *(const float4*)&num[(((size_t)c * N) + i) * OUT_F + o4 * 4];
    a0 += v.x; a1 += v.y; a2 += v.z; a3 += v.w;
  }

  if (d <= 0.f) {
    // row with zero neighbors: softmax degenerates to uniform 1/N
    a0 = a1 = a2 = a3 = 0.f;
    for (int j = 0; j < N; ++j) {
      a0 += bf2f(ht[(size_t)(o4 * 4 + 0) * N + j]);
      a1 += bf2f(ht[(size_t)(o4 * 4 + 1) * N + j]);
      a2 += bf2f(ht[(size_t)(o4 * 4 + 2) * N + j]);
      a3 += bf2f(ht[(size_t)(o4 * 4 + 3) * N + j]);
    }
    d = (float)N;
  }
  float inv = 1.f / d;
  a0 *= inv; a1 *= inv; a2 *= inv; a3 *= inv;
  float4 r4;
  r4.x = a0 > 0.f ? a0 : expm1f(a0);
  r4.y = a1 > 0.f ? a1 : expm1f(a1);
  r4.z = a2 > 0.f ? a2 : expm1f(a2);
  r4.w = a3 > 0.f ? a3 : expm1f(a3);
  *(float4*)&out[(size_t)i * OUT_F + o4 * 4] = r4;
}

extern "C" void kernel_launch(void* const* d_in, const int* in_sizes, int n_in,
                              void* d_out, int out_size, void* d_ws, size_t ws_size,
                              hipStream_t stream) {
  const float* input = (const float*)d_in[0];
  const int*   adj   = (const int*)d_in[1];
  const float* W     = (const float*)d_in[2];
  const float* a     = (const float*)d_in[3];
  float* out = (float*)d_out;

  unsigned short* ht = (unsigned short*)d_ws;        // N*64 bf16 = 1 MB
  float* f1 = (float*)(ht + (size_t)N * OUT_F);      // N
  float* f2 = f1 + N;                                // N
  float* bmax = f2 + N;                              // N/8 = 1024
  float* den = bmax + N / 8;                         // JC*N
  float* num = den + (size_t)JC * N;                 // JC*N*64
  size_t need = (size_t)((char*)(num + (size_t)JC * N * OUT_F) - (char*)d_ws);

  int jcc = (ws_size >= need) ? JC : 1;

  gat_prep<<<N / 8, 256, 0, stream>>>(input, W, a, ht, f1, f2, bmax);
  gat_part<<<jcc * (N / RB), TB, 0, stream>>>(adj, ht, f1, f2, bmax, num, den, jcc);
  gat_reduce<<<N / 16, 256, 0, stream>>>(ht, num, den, out, jcc);
}